// Round 6
// baseline (454.160 us; speedup 1.0000x reference)
//
#include <hip/hip_runtime.h>

constexpr float kEps = 1e-5f;

typedef float f2v __attribute__((ext_vector_type(2)));

__device__ __forceinline__ unsigned short f2bf(float x) {
  unsigned int u = __float_as_uint(x);
  unsigned int r = (u + 0x7fffu + ((u >> 16) & 1u)) >> 16;
  return (unsigned short)r;
}
__device__ __forceinline__ float bflo(unsigned int u) { return __uint_as_float(u << 16); }
__device__ __forceinline__ float bfhi(unsigned int u) { return __uint_as_float(u & 0xffff0000u); }
__device__ __forceinline__ unsigned int packbf(float a, float b) {
  return (unsigned int)f2bf(a) | ((unsigned int)f2bf(b) << 16);
}
__device__ __forceinline__ f2v fma2(f2v a, f2v b, f2v c) { return __builtin_elementwise_fma(a, b, c); }
__device__ __forceinline__ f2v splat2(float x) { f2v r; r.x = x; r.y = x; return r; }
__device__ __forceinline__ f2v unpk(unsigned int u) { f2v r; r.x = bflo(u); r.y = bfhi(u); return r; }
__device__ __forceinline__ f2v min2(f2v a, f2v b) { return __builtin_elementwise_min(a, b); }
__device__ __forceinline__ f2v max2(f2v a, f2v b) { return __builtin_elementwise_max(a, b); }

// ---------------- setup kernels ----------------

__global__ void zero_kernel(int* __restrict__ a, int* __restrict__ b,
                            float* __restrict__ bnb, int n) {
  int i = blockIdx.x * blockDim.x + threadIdx.x;
  if (i < n) { a[i] = 0; b[i] = 0; }
  if (i < 128) bnb[i] = 0.f;
}

__global__ void hist_kernel(const int* __restrict__ dst, int* __restrict__ deg, int E) {
  int e = blockIdx.x * blockDim.x + threadIdx.x;
  if (e < E) atomicAdd(&deg[dst[e]], 1);
}

__global__ void scan1_kernel(const int* __restrict__ deg, int* __restrict__ off,
                             int* __restrict__ part, int N) {
  __shared__ int sm[1024];
  int i = blockIdx.x * 1024 + threadIdx.x;
  int v = (i < N) ? deg[i] : 0;
  sm[threadIdx.x] = v;
  __syncthreads();
  for (int o = 1; o < 1024; o <<= 1) {
    int t = (threadIdx.x >= o) ? sm[threadIdx.x - o] : 0;
    __syncthreads();
    sm[threadIdx.x] += t;
    __syncthreads();
  }
  if (i < N) off[i] = sm[threadIdx.x] - v;   // exclusive
  if (threadIdx.x == 1023) part[blockIdx.x] = sm[1023];
}

__global__ void scan2_kernel(int* __restrict__ part, int* __restrict__ off, int nb, int N) {
  if (threadIdx.x == 0) {
    int run = 0;
    for (int b = 0; b < nb; b++) { int p = part[b]; part[b] = run; run += p; }
    off[N] = run;
  }
}

__global__ void scan3_kernel(int* __restrict__ off, const int* __restrict__ part, int N) {
  int i = blockIdx.x * 1024 + threadIdx.x;
  if (i < N) off[i] += part[blockIdx.x];
}

// CSR fill: scatter src/ew/eattr into slot order in one pass (edge order within
// node = atomic arrival order; perturbs fp reduction order at ulp level only)
__global__ void fill_kernel(const int* __restrict__ src, const int* __restrict__ dst,
                            const float* __restrict__ ew, const float4* __restrict__ eattr4,
                            const int* __restrict__ off, int* __restrict__ cnt,
                            int* __restrict__ srcs, float* __restrict__ ews,
                            float4* __restrict__ eattrg4, int E) {
  int e = blockIdx.x * blockDim.x + threadIdx.x;
  if (e < E) {
    int d = dst[e];
    int slot = off[d] + atomicAdd(&cnt[d], 1);
    srcs[slot] = src[e];
    ews[slot] = ew[e];
    float4 a = eattr4[e * 4 + 0], b = eattr4[e * 4 + 1];
    float4 c = eattr4[e * 4 + 2], q = eattr4[e * 4 + 3];
    eattrg4[(size_t)slot * 4 + 0] = a;
    eattrg4[(size_t)slot * 4 + 1] = b;
    eattrg4[(size_t)slot * 4 + 2] = c;
    eattrg4[(size_t)slot * 4 + 3] = q;
  }
}

__global__ void adl_kernel(const int* __restrict__ deg, float* __restrict__ adl, int N) {
  __shared__ float sm[1024];
  float s = 0.f;
  for (int n = threadIdx.x; n < N; n += 1024) s += logf((float)deg[n] + 1.f);
  sm[threadIdx.x] = s;
  __syncthreads();
  for (int o = 512; o > 0; o >>= 1) {
    if (threadIdx.x < o) sm[threadIdx.x] += sm[threadIdx.x + o];
    __syncthreads();
  }
  if (threadIdx.x == 0) adl[0] = sm[0];   // sum of log(deg+1); consumers divide by N
}

// h0 = x @ node_W + node_b   (x: [N,128], W: [128,32])
__global__ void node_emb_kernel(const float* __restrict__ x, const float* __restrict__ W,
                                const float* __restrict__ b, float* __restrict__ h, int N) {
  int n = blockIdx.x * 8 + (threadIdx.x >> 5);
  int j = threadIdx.x & 31;
  if (n >= N) return;
  float acc = b[j];
  const float4* x4 = (const float4*)(x + (size_t)n * 128);
#pragma unroll
  for (int q = 0; q < 32; q++) {
    float4 v = x4[q];
    acc += v.x * W[(4 * q + 0) * 32 + j];
    acc += v.y * W[(4 * q + 1) * 32 + j];
    acc += v.z * W[(4 * q + 2) * 32 + j];
    acc += v.w * W[(4 * q + 3) * 32 + j];
  }
  h[n * 32 + j] = acc;
}

// Fold edge path: Wf[l,t] = (edge_W @ enc_W[l]) @ pre_W[l,t,64:96,:]  (16x32)
__global__ void fuse_kernel(const float* __restrict__ edge_W, const float* __restrict__ edge_b,
                            const float* __restrict__ enc_W, const float* __restrict__ enc_b,
                            const float* __restrict__ pre_W, const float* __restrict__ pre_b,
                            float* __restrict__ Wf, float* __restrict__ bf) {
  __shared__ float tW[2][16][32];
  __shared__ float tb[2][32];
  int tid = threadIdx.x;
  for (int i = tid; i < 1024; i += 256) {
    int l = i >> 9, r = (i >> 5) & 15, c = i & 31;
    float s = 0.f;
    for (int k = 0; k < 32; k++) s += edge_W[r * 32 + k] * enc_W[(l * 32 + k) * 32 + c];
    tW[l][r][c] = s;
  }
  for (int i = tid; i < 64; i += 256) {
    int l = i >> 5, c = i & 31;
    float s = enc_b[l * 32 + c];
    for (int k = 0; k < 32; k++) s += edge_b[k] * enc_W[(l * 32 + k) * 32 + c];
    tb[l][c] = s;
  }
  __syncthreads();
  for (int i = tid; i < 4096; i += 256) {
    int l = i >> 11, t = (i >> 9) & 3, r = (i >> 5) & 15, c = i & 31;
    float s = 0.f;
    for (int k = 0; k < 32; k++) s += tW[l][r][k] * pre_W[((l * 4 + t) * 96 + 64 + k) * 32 + c];
    Wf[i] = s;
  }
  for (int i = tid; i < 256; i += 256) {
    int l = i >> 7, t = (i >> 5) & 3, c = i & 31;
    float s = pre_b[(l * 4 + t) * 32 + c];
    for (int k = 0; k < 32; k++) s += tb[l][k] * pre_W[((l * 4 + t) * 96 + 64 + k) * 32 + c];
    bf[i] = s;
  }
}

// ---------------- per-layer: node pre-projection ----------------
__global__ __launch_bounds__(256) void prep_kernel(
    const float* __restrict__ h, const float* __restrict__ preW,
    const float* __restrict__ bfv, unsigned short* __restrict__ qB,
    unsigned short* __restrict__ AB, int N) {
  __shared__ float hs[16][32];
  int tid = threadIdx.x;
  int c = tid & 127, half = tid >> 7;
  int t = c >> 5, g = c & 31;
  float ws[32], wd[32];
  {
    const float* pS = preW + (t * 96 + 32) * 32 + g;
    const float* pD = preW + (t * 96) * 32 + g;
#pragma unroll
    for (int k = 0; k < 32; k++) { ws[k] = pS[k * 32]; wd[k] = pD[k * 32]; }
  }
  float bc = bfv[c];
  int base = blockIdx.x * 16;
  for (int i = tid; i < 512; i += 256) {
    int nn = i >> 5;
    hs[nn][i & 31] = (base + nn < N) ? h[(size_t)(base + nn) * 32 + (i & 31)] : 0.f;
  }
  __syncthreads();
#pragma unroll
  for (int nn = 0; nn < 8; ++nn) {
    int nl = half + 2 * nn;
    int n = base + nl;
    if (n >= N) continue;
    float qa = 0.f, Aa = bc;
#pragma unroll
    for (int k = 0; k < 32; k++) {
      float hk = hs[nl][k];
      qa = fmaf(hk, ws[k], qa);
      Aa = fmaf(hk, wd[k], Aa);
    }
    qB[(size_t)n * 128 + c] = f2bf(qa);
    AB[(size_t)n * 128 + c] = f2bf(Aa);
  }
}

// ---------------- fused BN-apply + next-layer pre-projection ----------------
__global__ __launch_bounds__(256) void bnprep_kernel(
    const float* __restrict__ pre, const float* __restrict__ bnv,
    const float* __restrict__ gamma, const float* __restrict__ beta,
    const float* __restrict__ preW, const float* __restrict__ bfv,
    float* __restrict__ h, unsigned short* __restrict__ qB,
    unsigned short* __restrict__ AB, int N) {
  __shared__ float hs[16][32];
  int tid = threadIdx.x;
  int base = blockIdx.x * 16;
  float invN = 1.f / (float)N;
  for (int idx = tid; idx < 512; idx += 256) {
    int nn = idx >> 5, j = idx & 31;
    int n = base + nn;
    float v = 0.f;
    if (n < N) {
      float mu = bnv[j] * invN;
      float var = bnv[32 + j] * invN - mu * mu;
      float is = rsqrtf(var + kEps);
      v = fmaxf((pre[(size_t)n * 32 + j] - mu) * is * gamma[j] + beta[j], 0.f);
      h[(size_t)n * 32 + j] = v;
    }
    hs[nn][j] = v;
  }
  int c = tid & 127, half = tid >> 7;
  int t = c >> 5, g = c & 31;
  float ws[32], wd[32];
  {
    const float* pS = preW + (t * 96 + 32) * 32 + g;
    const float* pD = preW + (t * 96) * 32 + g;
#pragma unroll
    for (int k = 0; k < 32; k++) { ws[k] = pS[k * 32]; wd[k] = pD[k * 32]; }
  }
  float bc = bfv[c];
  __syncthreads();
#pragma unroll
  for (int nn = 0; nn < 8; ++nn) {
    int nl = half + 2 * nn;
    int n = base + nl;
    if (n >= N) continue;
    float qa = 0.f, Aa = bc;
#pragma unroll
    for (int k = 0; k < 32; k++) {
      float hk = hs[nl][k];
      qa = fmaf(hk, ws[k], qa);
      Aa = fmaf(hk, wd[k], Aa);
    }
    qB[(size_t)n * 128 + c] = f2bf(qa);
    AB[(size_t)n * 128 + c] = f2bf(Aa);
  }
}

// ---------------- per-layer: fused batched aggregation (pk-math) ----------------
#define FOLDE(F, EA, EB, EC, ED)                                \
  F = fma2(splat2(EA.x), wf[0], F);  F = fma2(splat2(EA.y), wf[1], F);  \
  F = fma2(splat2(EA.z), wf[2], F);  F = fma2(splat2(EA.w), wf[3], F);  \
  F = fma2(splat2(EB.x), wf[4], F);  F = fma2(splat2(EB.y), wf[5], F);  \
  F = fma2(splat2(EB.z), wf[6], F);  F = fma2(splat2(EB.w), wf[7], F);  \
  F = fma2(splat2(EC.x), wf[8], F);  F = fma2(splat2(EC.y), wf[9], F);  \
  F = fma2(splat2(EC.z), wf[10], F); F = fma2(splat2(EC.w), wf[11], F); \
  F = fma2(splat2(ED.x), wf[12], F); F = fma2(splat2(ED.y), wf[13], F); \
  F = fma2(splat2(ED.z), wf[14], F); F = fma2(splat2(ED.w), wf[15], F);

#define STAT2(V)                                                \
  sum = sum + V; sq = fma2(V, V, sq); mn = min2(mn, V); mx = max2(mx, V);

__global__ __launch_bounds__(256, 3) void agg4_kernel(
    const unsigned int* __restrict__ qB, const unsigned int* __restrict__ AB,
    const int* __restrict__ coff, const int* __restrict__ srcs,
    const float* __restrict__ ews, const float* __restrict__ eattrg,
    const float* __restrict__ Wf, unsigned int* __restrict__ stats, int N) {
  int lane = threadIdx.x & 63;
  int n = (blockIdx.x * blockDim.x + threadIdx.x) >> 6;
  if (n >= N) return;
  int t = lane >> 4, g0 = (2 * lane) & 31;
  f2v wf[16];
  {
    const float* p = Wf + t * 512 + g0;
#pragma unroll
    for (int k = 0; k < 16; k++) { f2v r; r.x = p[k * 32]; r.y = p[k * 32 + 1]; wf[k] = r; }
  }
  f2v a = unpk(AB[(size_t)n * 64 + lane]);
  int beg = coff[n], end = coff[n + 1];
  int dg = end - beg;
  f2v sum = splat2(0.f), sq = splat2(0.f);
  f2v mn = splat2(1e30f), mx = splat2(-1e30f);

  int i = beg;
  int sc0 = 0, sc1 = 0, sc2 = 0, sc3 = 0;
  float w0 = 0.f, w1 = 0.f, w2 = 0.f, w3 = 0.f;
  if (i + 4 <= end) {
    sc0 = srcs[i]; sc1 = srcs[i + 1]; sc2 = srcs[i + 2]; sc3 = srcs[i + 3];
    w0 = ews[i]; w1 = ews[i + 1]; w2 = ews[i + 2]; w3 = ews[i + 3];
  }
  for (; i + 4 <= end; i += 4) {
    // ---- load cluster: 4 q-gathers + 16 eattr float4 + next-batch idx ----
    unsigned int q0 = qB[(size_t)sc0 * 64 + lane];
    unsigned int q1 = qB[(size_t)sc1 * 64 + lane];
    unsigned int q2 = qB[(size_t)sc2 * 64 + lane];
    unsigned int q3 = qB[(size_t)sc3 * 64 + lane];
    const float4* ep = (const float4*)(eattrg + (size_t)i * 16);
    float4 e0 = ep[0], e1 = ep[1], e2 = ep[2], e3 = ep[3];
    float4 e4 = ep[4], e5 = ep[5], e6 = ep[6], e7 = ep[7];
    float4 e8 = ep[8], e9 = ep[9], e10 = ep[10], e11 = ep[11];
    float4 e12 = ep[12], e13 = ep[13], e14 = ep[14], e15 = ep[15];
    float wc0 = w0, wc1 = w1, wc2 = w2, wc3 = w3;
    if (i + 8 <= end) {
      sc0 = srcs[i + 4]; sc1 = srcs[i + 5]; sc2 = srcs[i + 6]; sc3 = srcs[i + 7];
      w0 = ews[i + 4]; w1 = ews[i + 5]; w2 = ews[i + 6]; w3 = ews[i + 7];
    }
    __builtin_amdgcn_sched_barrier(0);   // pin: all loads issued before compute
    // ---- compute ----
    f2v f0 = splat2(0.f), f1 = splat2(0.f), f2_ = splat2(0.f), f3 = splat2(0.f);
    FOLDE(f0, e0, e1, e2, e3)
    FOLDE(f1, e4, e5, e6, e7)
    FOLDE(f2_, e8, e9, e10, e11)
    FOLDE(f3, e12, e13, e14, e15)
    f2v v;
    v = (a + unpk(q0) + f0) * splat2(wc0); STAT2(v)
    v = (a + unpk(q1) + f1) * splat2(wc1); STAT2(v)
    v = (a + unpk(q2) + f2_) * splat2(wc2); STAT2(v)
    v = (a + unpk(q3) + f3) * splat2(wc3); STAT2(v)
  }
  for (; i < end; ++i) {
    int s = srcs[i];
    float w = ews[i];
    unsigned int q = qB[(size_t)s * 64 + lane];
    const float4* ep = (const float4*)(eattrg + (size_t)i * 16);
    float4 ea = ep[0], eb = ep[1], ec = ep[2], ed = ep[3];
    f2v f = splat2(0.f);
    FOLDE(f, ea, eb, ec, ed)
    f2v v = (a + unpk(q) + f) * splat2(w);
    STAT2(v)
  }
  if (dg == 0) { mn = splat2(0.f); mx = splat2(0.f); }
  float inv = 1.f / (float)(dg > 0 ? dg : 1);
  f2v mean = sum * splat2(inv);
  f2v var = sq * splat2(inv) - mean * mean;
  float sd0 = sqrtf(fmaxf(var.x, 0.f) + kEps);
  float sd1 = sqrtf(fmaxf(var.y, 0.f) + kEps);
  unsigned int* sp = stats + (size_t)n * 256;
  sp[0 * 64 + lane] = packbf(mean.x, mean.y);
  sp[1 * 64 + lane] = packbf(mn.x, mn.y);
  sp[2 * 64 + lane] = packbf(mx.x, mx.y);
  sp[3 * 64 + lane] = packbf(sd0, sd1);
}

// ---------------- per-layer: post_nn + lin + BN partials ----------------
__global__ __launch_bounds__(256) void post_kernel(
    const float* __restrict__ h, const unsigned int* __restrict__ stats,
    const int* __restrict__ coff, const float* __restrict__ adl,
    const float* __restrict__ postW, const float* __restrict__ postB,
    const float* __restrict__ linW, const float* __restrict__ linB,
    float* __restrict__ pre, float* __restrict__ bn, int N) {
  __shared__ unsigned int pwp[208 * 32];   // rows paired (2r,2r+1): 26 KB
  __shared__ unsigned int stu[4][256];     // per-wave raw stats rows: 4 KB
  __shared__ float red[8][32];             // BN partial reduce: 1 KB
  int tid = threadIdx.x;
  for (int i = tid; i < 6656; i += 256) {
    int r = i >> 5, cc = i & 31, tP = cc >> 3, gq = cc & 7;
    float lo = postW[tP * 3328 + (2 * r) * 8 + gq];
    float hi = postW[tP * 3328 + (2 * r + 1) * 8 + gq];
    pwp[i] = packbf(lo, hi);
  }
  __syncthreads();

  int wave = tid >> 6, lane = tid & 63;
  int c = lane & 31, hh = lane >> 5;
  int tP = c >> 3;
  float adN = adl[0];
  float bs = 0.f, bq = 0.f;

  for (int n = blockIdx.x * 4 + wave; n < N; n += gridDim.x * 4) {
    {
      uint4 su = ((const uint4*)stats)[(size_t)n * 64 + lane];
      ((uint4*)stu[wave])[lane] = su;   // per-wave region: no block barrier needed
    }
    int dg = coff[n + 1] - coff[n];
    float degc = (float)(dg > 0 ? dg : 1);
    float ad = adN / (float)N;
    float ld = logf(degc + 1.f);
    float amp = ld / ad, att = ad / ld;

    float acc = (hh == 0) ? postB[tP * 8 + (c & 7)] : 0.f;
    const float4* h4 = (const float4*)(h + (size_t)n * 32);
#pragma unroll
    for (int q4 = 0; q4 < 4; q4++) {
      float4 hv = h4[hh * 4 + q4];
      int r0 = hh * 8 + q4 * 2;
      unsigned int u0 = pwp[r0 * 32 + c], u1 = pwp[(r0 + 1) * 32 + c];
      acc = fmaf(hv.x, bflo(u0), acc);
      acc = fmaf(hv.y, bfhi(u0), acc);
      acc = fmaf(hv.z, bflo(u1), acc);
      acc = fmaf(hv.w, bfhi(u1), acc);
    }
#pragma unroll 8
    for (int jj = 0; jj < 32; jj++) {
      int sIdx = hh * 2 + (jj >> 4);
      unsigned int sv = stu[wave][sIdx * 64 + tP * 16 + (jj & 15)];
      float v0 = bflo(sv), v1 = bfhi(sv);
      int rm = 16 + hh * 32 + jj, ra = 80 + hh * 32 + jj, rt = 144 + hh * 32 + jj;
      unsigned int um = pwp[rm * 32 + c];
      unsigned int ua = pwp[ra * 32 + c];
      unsigned int ut = pwp[rt * 32 + c];
      float w0 = bflo(um); w0 = fmaf(amp, bflo(ua), w0); w0 = fmaf(att, bflo(ut), w0);
      float w1 = bfhi(um); w1 = fmaf(amp, bfhi(ua), w1); w1 = fmaf(att, bfhi(ut), w1);
      acc = fmaf(v0, w0, acc);
      acc = fmaf(v1, w1, acc);
    }
    acc += __shfl_xor(acc, 32);
    float o = linB[c];
#pragma unroll
    for (int k = 0; k < 32; k++) {
      float a = __shfl(acc, k);
      o = fmaf(a, linW[k * 32 + c], o);
    }
    if (lane < 32) {
      pre[(size_t)n * 32 + c] = o;
      bs += o;
      bq = fmaf(o, o, bq);
    }
  }

  __syncthreads();
  if (lane < 32) {
    red[wave * 2 + 0][c] = bs;
    red[wave * 2 + 1][c] = bq;
  }
  __syncthreads();
  if (tid < 64) {
    int which = tid >> 5, cc = tid & 31;
    float s = red[0 * 2 + which][cc] + red[1 * 2 + which][cc] +
              red[2 * 2 + which][cc] + red[3 * 2 + which][cc];
    atomicAdd(&bn[which * 32 + cc], s);
  }
}

__global__ void bn_apply_kernel(const float* __restrict__ pre, const float* __restrict__ bn,
                                const float* __restrict__ gamma, const float* __restrict__ beta,
                                float* __restrict__ h, int N) {
  int i = blockIdx.x * 256 + threadIdx.x;
  if (i >= N * 32) return;
  int j = i & 31;
  float invN = 1.f / (float)N;
  float mu = bn[j] * invN;
  float var = bn[32 + j] * invN - mu * mu;
  float is = rsqrtf(var + kEps);
  float v = (pre[i] - mu) * is * gamma[j] + beta[j];
  h[i] = fmaxf(v, 0.f);
}

// ---------------- pooling + MLP ----------------

__device__ __forceinline__ int lower_bound_dev(const int* a, int n, int key) {
  int lo = 0, hi = n;
  while (lo < hi) {
    int m = (lo + hi) >> 1;
    if (a[m] < key) lo = m + 1; else hi = m;
  }
  return lo;
}

__global__ void pool_kernel(const float* __restrict__ h, const int* __restrict__ batch,
                            float* __restrict__ gp, int N) {
  int gi = blockIdx.x;  // 64 graphs
  int lo = lower_bound_dev(batch, N, gi);
  int hi = lower_bound_dev(batch, N, gi + 1);
  __shared__ float part[8][32];
  int j = threadIdx.x & 31, ch = threadIdx.x >> 5;
  float s = 0.f;
  for (int n = lo + ch; n < hi; n += 8) s += h[(size_t)n * 32 + j];
  part[ch][j] = s;
  __syncthreads();
  if (threadIdx.x < 32) {
    float t = 0.f;
    for (int c2 = 0; c2 < 8; c2++) t += part[c2][j];
    gp[gi * 32 + j] = t;
  }
}

__global__ void mlp_kernel(const float* __restrict__ gp,
                           const float* __restrict__ W1, const float* __restrict__ b1,
                           const float* __restrict__ W2, const float* __restrict__ b2,
                           const float* __restrict__ W3, const float* __restrict__ b3,
                           float* __restrict__ out) {
  __shared__ float g1[64 * 32];
  __shared__ float g2[64 * 16];
  int tid = threadIdx.x;  // 256
  for (int i = tid; i < 2048; i += 256) {
    int r = i >> 5, c = i & 31;
    float s = b1[c];
    for (int k = 0; k < 32; k++) s += gp[r * 32 + k] * W1[k * 32 + c];
    g1[i] = fmaxf(s, 0.f);
  }
  __syncthreads();
  for (int i = tid; i < 1024; i += 256) {
    int r = i >> 4, c = i & 15;
    float s = b2[c];
    for (int k = 0; k < 32; k++) s += g1[r * 32 + k] * W2[k * 16 + c];
    g2[i] = fmaxf(s, 0.f);
  }
  __syncthreads();
  if (tid < 64) {
    float s = b3[0];
    for (int k = 0; k < 16; k++) s += g2[tid * 16 + k] * W3[k];
    out[tid] = s;
  }
}

// ---------------- launch ----------------

extern "C" void kernel_launch(void* const* d_in, const int* in_sizes, int n_in,
                              void* d_out, int out_size, void* d_ws, size_t ws_size,
                              hipStream_t stream) {
  (void)n_in; (void)out_size; (void)ws_size;
  const float* x     = (const float*)d_in[0];
  const float* eattr = (const float*)d_in[1];
  const float* ew    = (const float*)d_in[2];
  const int*   eidx  = (const int*)d_in[3];
  const int*   batch = (const int*)d_in[4];
  const float* nodeW = (const float*)d_in[5];
  const float* nodeB = (const float*)d_in[6];
  const float* edgeW = (const float*)d_in[7];
  const float* edgeB = (const float*)d_in[8];
  const float* encW  = (const float*)d_in[9];
  const float* encB  = (const float*)d_in[10];
  const float* preW  = (const float*)d_in[11];
  const float* preB  = (const float*)d_in[12];
  const float* postW = (const float*)d_in[13];
  const float* postB = (const float*)d_in[14];
  const float* linW  = (const float*)d_in[15];
  const float* linB  = (const float*)d_in[16];
  const float* bnG   = (const float*)d_in[17];
  const float* bnB   = (const float*)d_in[18];
  const float* W1    = (const float*)d_in[19];
  const float* b1    = (const float*)d_in[20];
  const float* W2    = (const float*)d_in[21];
  const float* b2    = (const float*)d_in[22];
  const float* W3    = (const float*)d_in[23];
  const float* b3    = (const float*)d_in[24];
  float* out = (float*)d_out;

  int N = in_sizes[0] / 128;
  int E = in_sizes[2];
  const int* srcp = eidx;
  const int* dstp = eidx + E;

  char* wsb = (char*)d_ws;
  size_t woff = 0;
  auto alloc = [&](size_t bytes) -> void* {
    void* p = (void*)(wsb + woff);
    woff += (bytes + 255) & ~(size_t)255;
    return p;
  };
  int* deg   = (int*)alloc((size_t)N * 4);
  int* cnt   = (int*)alloc((size_t)N * 4);
  int* coff  = (int*)alloc((size_t)(N + 1) * 4);
  int* part  = (int*)alloc(64 * 4);
  int* srcs  = (int*)alloc((size_t)E * 4);
  float* ews = (float*)alloc((size_t)E * 4);
  float* eattrg = (float*)alloc((size_t)E * 16 * 4);
  float* h    = (float*)alloc((size_t)N * 32 * 4);
  float* pre  = (float*)alloc((size_t)N * 32 * 4);
  float* adl  = (float*)alloc(256);
  float* bnbuf = (float*)alloc(2 * 64 * 4);
  float* gp   = (float*)alloc(64 * 32 * 4);
  float* WfB  = (float*)alloc(2 * 4 * 16 * 32 * 4);
  float* bfB  = (float*)alloc(2 * 4 * 32 * 4);
  unsigned short* qB  = (unsigned short*)alloc((size_t)N * 128 * 2);
  unsigned short* AB  = (unsigned short*)alloc((size_t)N * 128 * 2);
  unsigned int* stats = (unsigned int*)alloc((size_t)N * 256 * 4);

  int nb = (N + 1023) / 1024;
  zero_kernel<<<(N + 255) / 256, 256, 0, stream>>>(deg, cnt, bnbuf, N);
  hist_kernel<<<(E + 255) / 256, 256, 0, stream>>>(dstp, deg, E);
  scan1_kernel<<<nb, 1024, 0, stream>>>(deg, coff, part, N);
  scan2_kernel<<<1, 64, 0, stream>>>(part, coff, nb, N);
  scan3_kernel<<<nb, 1024, 0, stream>>>(coff, part, N);
  fill_kernel<<<(E + 255) / 256, 256, 0, stream>>>(srcp, dstp, ew, (const float4*)eattr,
                                                   coff, cnt, srcs, ews, (float4*)eattrg, E);
  adl_kernel<<<1, 1024, 0, stream>>>(deg, adl, N);
  node_emb_kernel<<<(N + 7) / 8, 256, 0, stream>>>(x, nodeW, nodeB, h, N);
  fuse_kernel<<<1, 256, 0, stream>>>(edgeW, edgeB, encW, encB, preW, preB, WfB, bfB);

  // layer 0
  prep_kernel<<<(N + 15) / 16, 256, 0, stream>>>(h, preW, bfB, qB, AB, N);
  agg4_kernel<<<(N + 3) / 4, 256, 0, stream>>>(
      (const unsigned int*)qB, (const unsigned int*)AB, coff, srcs, ews,
      eattrg, WfB, stats, N);
  post_kernel<<<1280, 256, 0, stream>>>(
      h, stats, coff, adl, postW, postB, linW, linB, pre, bnbuf, N);
  // fused bn_apply(l0) + prep(l1)
  bnprep_kernel<<<(N + 15) / 16, 256, 0, stream>>>(
      pre, bnbuf, bnG, bnB, preW + 12288, bfB + 128, h, qB, AB, N);
  // layer 1
  agg4_kernel<<<(N + 3) / 4, 256, 0, stream>>>(
      (const unsigned int*)qB, (const unsigned int*)AB, coff, srcs, ews,
      eattrg, WfB + 2048, stats, N);
  post_kernel<<<1280, 256, 0, stream>>>(
      h, stats, coff, adl, postW + 13312, postB + 32, linW + 1024, linB + 32,
      pre, bnbuf + 64, N);
  bn_apply_kernel<<<(N * 32 + 255) / 256, 256, 0, stream>>>(
      pre, bnbuf + 64, bnG + 32, bnB + 32, h, N);

  pool_kernel<<<64, 256, 0, stream>>>(h, batch, gp, N);
  mlp_kernel<<<1, 256, 0, stream>>>(gp, W1, b1, W2, b2, W3, b3, out);
}